// Round 13
// baseline (272.297 us; speedup 1.0000x reference)
//
#include <hip/hip_runtime.h>
#include <math.h>

constexpr int N_  = 50000;
constexpr int E_  = 500000;
constexpr int NB_ = (N_ + 255) / 256;   // 196 scan blocks

typedef unsigned short u16;
typedef unsigned int u32;
typedef short short8 __attribute__((ext_vector_type(8)));
typedef __bf16 bf16x8 __attribute__((ext_vector_type(8)));
typedef float f32x4 __attribute__((ext_vector_type(4)));
typedef short short4v __attribute__((ext_vector_type(4)));

#define DINL __device__ __forceinline__

DINL float gelu_f(float x) { return 0.5f * x * (1.f + erff(x * 0.70710678118654752f)); }
DINL float sigmoid_f(float x) { return 1.f / (1.f + expf(-x)); }
DINL u16 f2b(float x) {            // f32 -> bf16 RNE
  unsigned u = __float_as_uint(x);
  return (u16)((u + 0x7FFFu + ((u >> 16) & 1u)) >> 16);
}
DINL float b2f(u16 b) { return __uint_as_float(((unsigned)b) << 16); }

template <int CTRL>
DINL float dpp_add(float c) {
  int p = __builtin_amdgcn_update_dpp(0, __builtin_bit_cast(int, c), CTRL, 0xf, 0xf, false);
  return c + __builtin_bit_cast(float, p);
}
// sum over each 16-lane group — all DPP (VALU pipe)
DINL float reduce16(float c) {
  c = dpp_add<0xB1>(c);    // quad_perm [1,0,3,2] : xor1
  c = dpp_add<0x4E>(c);    // quad_perm [2,3,0,1] : xor2
  c = dpp_add<0x141>(c);   // row_half_mirror
  c = dpp_add<0x140>(c);   // row_mirror
  return c;
}

// ================= CSR build =================
__global__ void deg_int_kernel(const int* __restrict__ dst, int* __restrict__ deg) {
  int t = blockIdx.x * 256 + threadIdx.x;
  if (t < E_) atomicAdd(&deg[dst[t]], 1);
}

__global__ __launch_bounds__(256) void scan_local(const int* __restrict__ deg,
    int* __restrict__ rowptr, int* __restrict__ bsum) {
  __shared__ int sums[4];
  const int tid = threadIdx.x, lane = tid & 63, wid = tid >> 6;
  const int i = blockIdx.x * 256 + tid;
  int v = (i < N_) ? deg[i] : 0;
  int x = v;
#pragma unroll
  for (int o = 1; o < 64; o <<= 1) { int y = __shfl_up(x, o); if (lane >= o) x += y; }
  if (lane == 63) sums[wid] = x;
  __syncthreads();
  int woff = 0;
#pragma unroll
  for (int w = 0; w < 3; ++w) if (w < wid) woff += sums[w];
  if (i < N_) rowptr[i] = x - v + woff;
  if (tid == 255) bsum[blockIdx.x] = woff + x;
}

__global__ __launch_bounds__(256) void scan_block(const int* __restrict__ bsum,
                                                  int* __restrict__ bpre) {
  __shared__ int sums[4];
  const int tid = threadIdx.x, lane = tid & 63, wid = tid >> 6;
  int v = (tid < NB_) ? bsum[tid] : 0;
  int x = v;
#pragma unroll
  for (int o = 1; o < 64; o <<= 1) { int y = __shfl_up(x, o); if (lane >= o) x += y; }
  if (lane == 63) sums[wid] = x;
  __syncthreads();
  int woff = 0;
#pragma unroll
  for (int w = 0; w < 3; ++w) if (w < wid) woff += sums[w];
  if (tid < NB_) bpre[tid] = x - v + woff;
  if (tid == 255) bpre[NB_] = woff + x;
}

__global__ __launch_bounds__(256) void scan_add(int* __restrict__ rowptr,
                                                const int* __restrict__ bpre) {
  int i = blockIdx.x * 256 + threadIdx.x;
  if (i < N_) rowptr[i] += bpre[i >> 8];
  else if (i == N_) rowptr[N_] = bpre[NB_];
}

__global__ void csr_fill(const int* __restrict__ src, const int* __restrict__ dst,
                         const int* __restrict__ rowptr, int* __restrict__ cursor,
                         int* __restrict__ colsrc) {
  int e = blockIdx.x * 256 + threadIdx.x;
  if (e >= E_) return;
  int d = dst[e];
  int pos = rowptr[d] + atomicAdd(&cursor[d], 1);
  colsrc[pos] = src[e];
}

// ================= packing =================
__global__ __launch_bounds__(256) void pack_feat(const float* __restrict__ f,
                                                 u16* __restrict__ o) {
  int t = blockIdx.x * 256 + threadIdx.x;
  float4 v = ((const float4*)f)[t];
  short4v r;
  r[0] = (short)f2b(v.x); r[1] = (short)f2b(v.y);
  r[2] = (short)f2b(v.z); r[3] = (short)f2b(v.w);
  ((short4v*)o)[t] = r;
}

// pack weights into MFMA fragment order:
// dst[((ct*(K/32)+ks)*64+lane)*8+j] = W[ks*32+(lane>>4)*8+j][ct*16+(lane&15)]
// S1/S2 are C-concat duals now: [Wself|Wneigh] side by side (C=128).
__global__ __launch_bounds__(256) void pack_w(
    const float* __restrict__ Wmt, const float* __restrict__ Wms,
    const float* __restrict__ W1s, const float* __restrict__ W1n,
    const float* __restrict__ W2s, const float* __restrict__ W2n,
    const float* __restrict__ g1Ws, const float* __restrict__ g1Wd,
    const float* __restrict__ g2Ws, const float* __restrict__ g2Wd,
    const float* __restrict__ W3, u16* __restrict__ dst) {
  int e = blockIdx.x * 256 + threadIdx.x;
  const float *Wa, *Wb = nullptr;
  int K1, K2 = 0, Ca, Cb = 0, st;
  if (e < 16384)       { Wa = Wmt;  K1 = 128; Ca = 128;           st = 0; }
  else if (e < 32768)  { Wa = Wms;  K1 = 128; Ca = 128;           st = 16384; }
  else if (e < 49152)  { Wa = W1s;  Wb = W1n; K1 = 128; Ca = 64; Cb = 64; st = 32768; }
  else if (e < 57344)  { Wa = W2s;  Wb = W2n; K1 = 64;  Ca = 64; Cb = 64; st = 49152; }
  else if (e < 90112)  { Wa = g1Ws; Wb = g1Wd; K1 = 128; Ca = 128; Cb = 128; st = 57344; }
  else if (e < 106496) { Wa = g2Ws; Wb = g2Wd; K1 = 64;  Ca = 128; Cb = 128; st = 90112; }
  else                 { Wa = W3;   K1 = 192; Ca = 64;            st = 106496; }
  int el = e - st;
  int Kt = K1 + K2;
  int ct = el / (Kt * 16);
  int rem = el - ct * Kt * 16;
  int ks = rem >> 9, rem2 = rem & 511, lane = rem2 >> 3, j = rem2 & 7;
  int k = ks * 32 + ((lane >> 4) << 3) + j;
  int c = ct * 16 + (lane & 15);
  float v;
  if (k < K1) v = (c < Ca) ? Wa[k * Ca + c] : Wb[k * Cb + (c - Ca)];
  else        v = Wb[(k - K1) * Ca + c];
  dst[e] = f2b(v);
}

// ================= MFMA GEMM (8 waves: col-quadrant x row-half split) =============
template <int K1, int K2, int C, int EPI>
__global__ __launch_bounds__(512) void gemm_mfma(
    const u16* __restrict__ A1, const u16* __restrict__ A2,
    const u16* __restrict__ Wp, const float* __restrict__ bias,
    const float* __restrict__ bias2, const float* __restrict__ mulf,
    void* __restrict__ outv, void* __restrict__ outv2) {
  constexpr int K = K1 + K2, KS = K / 32, CT4 = C / 64;
  constexpr int NCH1 = K1 / 8, NCH2 = K2 / 8;
  __shared__ u16 alds[64 * K];
  const int tid = threadIdx.x;
  const int w = tid >> 6, l = tid & 63;
  const int cq = w >> 1, rh = w & 1;
  const int wr0 = blockIdx.x * 64;

  short8 wfrag[KS][CT4];
#pragma unroll
  for (int ks = 0; ks < KS; ++ks)
#pragma unroll
    for (int c4 = 0; c4 < CT4; ++c4)
      wfrag[ks][c4] = *(const short8*)(Wp +
          ((size_t)((cq * CT4 + c4) * KS + ks) * 64 + l) * 8);

  for (int i = tid; i < 64 * NCH1; i += 512) {
    int rr = i / NCH1, kc = i % NCH1;
    int gr = wr0 + rr; if (gr >= N_) gr = N_ - 1;
    short8 v = *(const short8*)(A1 + (long)gr * K1 + kc * 8);
    *(short8*)&alds[rr * K + ((kc ^ (rr & 7)) << 3)] = v;
  }
  if constexpr (K2 > 0) {
    for (int i = tid; i < 64 * NCH2; i += 512) {
      int rr = i / NCH2, kc = i % NCH2;
      int gr = wr0 + rr; if (gr >= N_) gr = N_ - 1;
      short8 v = *(const short8*)(A2 + (long)gr * K2 + kc * 8);
      *(short8*)&alds[rr * K + (((NCH1 + kc) ^ (rr & 7)) << 3)] = v;
    }
  }
  __syncthreads();

  f32x4 acc[2][CT4];
#pragma unroll
  for (int rr = 0; rr < 2; ++rr)
#pragma unroll
    for (int c4 = 0; c4 < CT4; ++c4) acc[rr][c4] = (f32x4){0.f, 0.f, 0.f, 0.f};

#pragma unroll
  for (int ks = 0; ks < KS; ++ks) {
#pragma unroll
    for (int rr = 0; rr < 2; ++rr) {
      const int nr = (rh * 2 + rr) * 16 + (l & 15);
      const int ch = (ks * 4 + (l >> 4)) ^ (nr & 7);
      short8 av = *(const short8*)&alds[nr * K + (ch << 3)];
      bf16x8 bf = __builtin_bit_cast(bf16x8, av);
#pragma unroll
      for (int c4 = 0; c4 < CT4; ++c4)
        acc[rr][c4] = __builtin_amdgcn_mfma_f32_16x16x32_bf16(
            __builtin_bit_cast(bf16x8, wfrag[ks][c4]), bf, acc[rr][c4], 0, 0, 0);
    }
  }

  const int colq = (l >> 4) << 2;
  if constexpr (EPI == 0) {
    u16* out = (u16*)outv;
#pragma unroll
    for (int rr = 0; rr < 2; ++rr) {
      int row = wr0 + (rh * 2 + rr) * 16 + (l & 15);
      if (row >= N_) continue;
#pragma unroll
      for (int c4 = 0; c4 < CT4; ++c4) {
        int colb = (cq * CT4 + c4) * 16 + colq;
        short4v s;
#pragma unroll
        for (int r = 0; r < 4; ++r) s[r] = (short)f2b(acc[rr][c4][r]);
        *(short4v*)(out + (long)row * C + colb) = s;
      }
    }
  } else if constexpr (EPI == 4) {          // C=64: leaky + row l2norm (f32 out)
    __shared__ float ssb[64][4];
    float* out = (float*)outv;
    const int colb = cq * 16 + colq;
    float4 bv = *(const float4*)(bias + colb);
    float xv[2][4];
#pragma unroll
    for (int rr = 0; rr < 2; ++rr) {
      float ss = 0.f;
#pragma unroll
      for (int r = 0; r < 4; ++r) {
        float x = acc[rr][0][r] + ((const float*)&bv)[r];
        x = fmaxf(x, 0.01f * x);
        xv[rr][r] = x; ss += x * x;
      }
      ss += __shfl_xor(ss, 16);
      ss += __shfl_xor(ss, 32);
      if (l < 16) ssb[(rh * 2 + rr) * 16 + l][cq] = ss;
    }
    __syncthreads();
#pragma unroll
    for (int rr = 0; rr < 2; ++rr) {
      int nl = (rh * 2 + rr) * 16 + (l & 15);
      int row = wr0 + nl;
      if (row >= N_) continue;
      float ss = ssb[nl][0] + ssb[nl][1] + ssb[nl][2] + ssb[nl][3];
      float sc = 1.f / fmaxf(sqrtf(ss), 1e-12f);
      float4 o;
#pragma unroll
      for (int r = 0; r < 4; ++r) ((float*)&o)[r] = xv[rr][r] * sc;
      *(float4*)(out + (long)row * 64 + colb) = o;
    }
  } else {                                  // EPI == 5: dual mask (C=256, K=128)
#pragma unroll
    for (int c4 = 0; c4 < CT4; ++c4) {
      const int ct = cq * CT4 + c4;
      const bool lo = ct < 8;
      u16* op = lo ? (u16*)outv : (u16*)outv2;
      const int ccb = (ct & 7) * 16 + colq;
      float4 bv = *(const float4*)((lo ? bias : bias2) + ccb);
#pragma unroll
      for (int rr = 0; rr < 2; ++rr) {
        int nl = (rh * 2 + rr) * 16 + (l & 15);
        int row = wr0 + nl;
        if (row >= N_) continue;
        int ch = (ccb >> 3) ^ (nl & 7);
        short4v fq = *(const short4v*)&alds[nl * K + (ch << 3) + (ccb & 7)];
        short4v s;
#pragma unroll
        for (int r = 0; r < 4; ++r) {
          float x = acc[rr][c4][r] + ((const float*)&bv)[r];
          float fv = b2f((u16)fq[r]);
          s[r] = (short)f2b(fv * sigmoid_f(x));
        }
        *(short4v*)(op + (long)row * 128 + ccb) = s;
      }
    }
  }
}

// ================= fused SAGE gather + epilogue =================
// qp row: [q (64 cols) | p (64 cols)].  out = gelu(q + mean_src(p) + b) (*drop)
// quarter-split: 16 lanes cover p row (128 B/edge), 4 quarter-groups = 4 edges/step.
template <bool DROP>
__global__ __launch_bounds__(256) void gather_sage(const u16* __restrict__ qp,
    const int* __restrict__ rowptr, const int* __restrict__ colsrc,
    const float* __restrict__ bias, const float* __restrict__ drop,
    u16* __restrict__ out) {
  int node = blockIdx.x * 4 + (threadIdx.x >> 6);
  int l = threadIdx.x & 63;
  int ql = l & 15, qg = l >> 4;
  int beg = rowptr[node], end = rowptr[node + 1];
  const int off = 4 * ql;
  float a0 = 0.f, a1 = 0.f, a2 = 0.f, a3 = 0.f;
  float b0 = 0.f, b1 = 0.f, b2 = 0.f, b3 = 0.f;
  int j = beg;
  for (; j + 8 <= end; j += 8) {
    int s0 = colsrc[j + qg], s1 = colsrc[j + 4 + qg];
    uint2 v0 = *(const uint2*)(qp + (size_t)s0 * 128 + 64 + off);
    uint2 v1 = *(const uint2*)(qp + (size_t)s1 * 128 + 64 + off);
    a0 += b2f((u16)(v0.x & 0xffffu));
    a1 += b2f((u16)(v0.x >> 16));
    a2 += b2f((u16)(v0.y & 0xffffu));
    a3 += b2f((u16)(v0.y >> 16));
    b0 += b2f((u16)(v1.x & 0xffffu));
    b1 += b2f((u16)(v1.x >> 16));
    b2 += b2f((u16)(v1.y & 0xffffu));
    b3 += b2f((u16)(v1.y >> 16));
  }
  for (; j < end; j += 4) {
    int idx = j + qg;
    bool valid = idx < end;
    int s = colsrc[valid ? idx : end - 1];
    uint2 v = *(const uint2*)(qp + (size_t)s * 128 + 64 + off);
    if (!valid) { v.x = 0; v.y = 0; }
    a0 += b2f((u16)(v.x & 0xffffu));
    a1 += b2f((u16)(v.x >> 16));
    a2 += b2f((u16)(v.y & 0xffffu));
    a3 += b2f((u16)(v.y >> 16));
  }
  a0 += b0; a1 += b1; a2 += b2; a3 += b3;
  a0 += __shfl_xor(a0, 32); a1 += __shfl_xor(a1, 32);
  a2 += __shfl_xor(a2, 32); a3 += __shfl_xor(a3, 32);
  a0 += __shfl_xor(a0, 16); a1 += __shfl_xor(a1, 16);
  a2 += __shfl_xor(a2, 16); a3 += __shfl_xor(a3, 16);
  if (l < 16) {
    float inv = 1.f / fmaxf((float)(end - beg), 1.f);
    uint2 qv = *(const uint2*)(qp + (size_t)node * 128 + off);
    float4 bv = *(const float4*)(bias + off);
    float g0 = gelu_f(b2f((u16)(qv.x & 0xffffu)) + a0 * inv + bv.x);
    float g1 = gelu_f(b2f((u16)(qv.x >> 16))     + a1 * inv + bv.y);
    float g2 = gelu_f(b2f((u16)(qv.y & 0xffffu)) + a2 * inv + bv.z);
    float g3 = gelu_f(b2f((u16)(qv.y >> 16))     + a3 * inv + bv.w);
    if constexpr (DROP) {
      float4 dv = *(const float4*)(drop + (long)node * 64 + off);
      g0 *= dv.x; g1 *= dv.y; g2 *= dv.z; g3 *= dv.w;
    }
    short4v s;
    s[0] = (short)f2b(g0); s[1] = (short)f2b(g1);
    s[2] = (short)f2b(g2); s[3] = (short)f2b(g3);
    *(short4v*)(out + (long)node * 64 + off) = s;
  }
}

// ================= fused GATv2: half-split, 16-lane DPP reduce ===================
template <bool LAYER1>
__global__ __launch_bounds__(256) void gat_fused(const u16* __restrict__ fsfd,
    const int* __restrict__ rowptr, const int* __restrict__ colsrc,
    const float* __restrict__ attn, const float* __restrict__ bias,
    const float* __restrict__ drop, void* __restrict__ outv) {
  int node = blockIdx.x * 4 + (threadIdx.x >> 6);
  int l = threadIdx.x & 63;
  int hl = l & 31, half = l >> 5;
  const int off = 4 * hl;
  float4 av = *(const float4*)(attn + off);
  uint2 fdv = *(const uint2*)(fsfd + (size_t)node * 256 + 128 + off);
  float fd0 = b2f((u16)(fdv.x & 0xffffu)), fd1 = b2f((u16)(fdv.x >> 16));
  float fd2 = b2f((u16)(fdv.y & 0xffffu)), fd3 = b2f((u16)(fdv.y >> 16));
  float d_own = 0.f, acc0 = 0.f, acc1 = 0.f, acc2 = 0.f, acc3 = 0.f;

  auto edge = [&](uint2 v, float m) {
    float f0 = b2f((u16)(v.x & 0xffffu)), f1 = b2f((u16)(v.x >> 16));
    float f2 = b2f((u16)(v.y & 0xffffu)), f3 = b2f((u16)(v.y >> 16));
    float t0 = f0 + fd0, t1 = f1 + fd1, t2 = f2 + fd2, t3 = f3 + fd3;
    t0 = fmaxf(t0, 0.2f * t0); t1 = fmaxf(t1, 0.2f * t1);
    t2 = fmaxf(t2, 0.2f * t2); t3 = fmaxf(t3, 0.2f * t3);
    float c = t0 * av.x + t1 * av.y + t2 * av.z + t3 * av.w;
    c = reduce16(c);
    float e = __expf(c) * m;
    d_own += e;
    acc0 += e * f0; acc1 += e * f1; acc2 += e * f2; acc3 += e * f3;
  };

  const int beg = rowptr[node], end = rowptr[node + 1];
  int j = beg;
  for (; j + 8 <= end; j += 8) {
    int sa = colsrc[j + half],     sb = colsrc[j + 2 + half];
    int sc = colsrc[j + 4 + half], sd = colsrc[j + 6 + half];
    uint2 va = *(const uint2*)(fsfd + (size_t)sa * 256 + off);
    uint2 vb = *(const uint2*)(fsfd + (size_t)sb * 256 + off);
    uint2 vc = *(const uint2*)(fsfd + (size_t)sc * 256 + off);
    uint2 vd = *(const uint2*)(fsfd + (size_t)sd * 256 + off);
    edge(va, 1.f); edge(vb, 1.f); edge(vc, 1.f); edge(vd, 1.f);
  }
  for (; j < end; j += 2) {
    int idx = j + half;
    bool valid = idx < end;
    int s = colsrc[valid ? idx : end - 1];
    uint2 v = *(const uint2*)(fsfd + (size_t)s * 256 + off);
    if (!valid) { v.x = 0; v.y = 0; }
    edge(v, valid ? 1.f : 0.f);
  }

  acc0 += __shfl_xor(acc0, 32); acc1 += __shfl_xor(acc1, 32);
  acc2 += __shfl_xor(acc2, 32); acc3 += __shfl_xor(acc3, 32);
  d_own += __shfl_xor(d_own, 32);

  float4 bv = *(const float4*)(bias + off);
  float inv = d_own > 0.f ? 1.f / d_own : 0.f;
  float g0 = gelu_f(bv.x + acc0 * inv);
  float g1 = gelu_f(bv.y + acc1 * inv);
  float g2 = gelu_f(bv.z + acc2 * inv);
  float g3 = gelu_f(bv.w + acc3 * inv);
  float v0 = 0.5f * (g0 + __shfl_xor(g0, 16));
  float v1 = 0.5f * (g1 + __shfl_xor(g1, 16));
  float v2 = 0.5f * (g2 + __shfl_xor(g2, 16));
  float v3 = 0.5f * (g3 + __shfl_xor(g3, 16));
  if constexpr (LAYER1) {
    if (l < 16) {
      float4 dv = *(const float4*)(drop + (long)node * 64 + 4 * l);
      short4v s;
      s[0] = (short)f2b(v0 * dv.x); s[1] = (short)f2b(v1 * dv.y);
      s[2] = (short)f2b(v2 * dv.z); s[3] = (short)f2b(v3 * dv.w);
      *(short4v*)((u16*)outv + (long)node * 64 + 4 * l) = s;
    }
  } else {
    float ss = v0 * v0 + v1 * v1 + v2 * v2 + v3 * v3;
    ss = reduce16(ss);
    float sc = 1.f / fmaxf(sqrtf(ss), 1e-12f);
    if (l < 16) {
      float4 o; o.x = v0 * sc; o.y = v1 * sc; o.z = v2 * sc; o.w = v3 * sc;
      *(float4*)((float*)outv + (long)node * 64 + 4 * l) = o;
    }
  }
}

extern "C" void kernel_launch(void* const* d_in, const int* in_sizes, int n_in,
                              void* d_out, int out_size, void* d_ws, size_t ws_size,
                              hipStream_t stream) {
  const float* feat = (const float*)d_in[0];
  const int*   esrc = (const int*)d_in[1];
  const int*   edst = (const int*)d_in[2];
  const float* Wmt = (const float*)d_in[3],  *bmt = (const float*)d_in[4];
  const float* Wms = (const float*)d_in[5],  *bms = (const float*)d_in[6];
  const float* W1s = (const float*)d_in[7],  *W1n = (const float*)d_in[8],  *b1 = (const float*)d_in[9];
  const float* W2s = (const float*)d_in[10], *W2n = (const float*)d_in[11], *b2 = (const float*)d_in[12];
  const float* g1Ws = (const float*)d_in[13], *g1Wd = (const float*)d_in[14];
  const float* g1a  = (const float*)d_in[15], *g1b  = (const float*)d_in[16];
  const float* g2Ws = (const float*)d_in[17], *g2Wd = (const float*)d_in[18];
  const float* g2a  = (const float*)d_in[19], *g2b  = (const float*)d_in[20];
  const float* W3  = (const float*)d_in[21], *b3 = (const float*)d_in[22];
  const float* dropt = (const float*)d_in[23], *drops = (const float*)d_in[24];

  float* out_t = (float*)d_out;
  float* out_s = out_t + (long)N_ * 64;

  // workspace (u16 units)
  u16* wsh = (u16*)d_ws;
  u16* featbf = wsh;                 // N*128
  u16* hbuf_t = wsh +  6400000;      // N*128
  u16* hbuf_s = wsh + 12800000;      // N*128
  u16* qp1    = wsh + 19200000;      // N*128  [q1|p1]
  u16* h1     = wsh + 25600000;      // N*64
  u16* qp2    = wsh + 28800000;      // N*128  [q2|p2]
  u16* h2     = wsh + 35200000;      // N*64
  u16* hs1    = wsh + 38400000;      // N*64
  u16* fsfd   = wsh + 41600000;      // N*256
  u16* Wpk    = wsh + 54400000;      // 118784
  int* degi   = (int*)(wsh + 54518784);  // N
  int* cursor = degi + N_;               // N
  int* rowptr = cursor + N_;             // N+1
  int* colsrc = rowptr + N_ + 1;         // E
  int* bsum   = colsrc + E_;             // NB_
  int* bpre   = bsum + NB_;              // NB_+1

  const u16* WpMT = Wpk;             // [Wmt|Wms]
  const u16* WpS1 = Wpk + 32768;     // [W1s|W1n] C-concat
  const u16* WpS2 = Wpk + 49152;     // [W2s|W2n] C-concat
  const u16* WpG1 = Wpk + 57344;
  const u16* WpG2 = Wpk + 90112;
  const u16* WpW3 = Wpk + 106496;

  constexpr int GB = (N_ + 63) / 64;

  // ---- CSR + packing ----
  (void)hipMemsetAsync(degi, 0, (size_t)(2 * N_) * sizeof(int), stream);
  deg_int_kernel<<<(E_ + 255) / 256, 256, 0, stream>>>(edst, degi);
  scan_local<<<NB_, 256, 0, stream>>>(degi, rowptr, bsum);
  scan_block<<<1, 256, 0, stream>>>(bsum, bpre);
  scan_add<<<(N_ + 256) / 256, 256, 0, stream>>>(rowptr, bpre);
  csr_fill<<<(E_ + 255) / 256, 256, 0, stream>>>(esrc, edst, rowptr, cursor, colsrc);
  pack_feat<<<N_ * 128 / 4 / 256, 256, 0, stream>>>(feat, featbf);
  pack_w<<<464, 256, 0, stream>>>(Wmt, Wms, W1s, W1n, W2s, W2n,
                                  g1Ws, g1Wd, g2Ws, g2Wd, W3, Wpk);

  // ---- both feature masks in one GEMM ----
  gemm_mfma<128, 0, 256, 5><<<GB, 512, 0, stream>>>(featbf, nullptr, WpMT, bmt, bms,
                                                    nullptr, hbuf_t, hbuf_s);

  // ---- topology branch (SAGE, pre-multiplied gather) ----
  gemm_mfma<128, 0, 128, 0><<<GB, 512, 0, stream>>>(hbuf_t, nullptr, WpS1, nullptr, nullptr,
                                                    nullptr, qp1, nullptr);
  gather_sage<true><<<N_ / 4, 256, 0, stream>>>(qp1, rowptr, colsrc, b1, dropt, h1);
  gemm_mfma<64, 0, 128, 0><<<GB, 512, 0, stream>>>(h1, nullptr, WpS2, nullptr, nullptr,
                                                   nullptr, qp2, nullptr);
  gather_sage<false><<<N_ / 4, 256, 0, stream>>>(qp2, rowptr, colsrc, b2, nullptr, h2);
  gemm_mfma<64, 128, 64, 4><<<GB, 512, 0, stream>>>(h2, featbf, WpW3, b3, nullptr,
                                                    nullptr, out_t, nullptr);

  // ---- semantic branch (GATv2) ----
  gemm_mfma<128, 0, 256, 0><<<GB, 512, 0, stream>>>(hbuf_s, nullptr, WpG1, nullptr, nullptr,
                                                    nullptr, fsfd, nullptr);
  gat_fused<true><<<N_ / 4, 256, 0, stream>>>(fsfd, rowptr, colsrc, g1a, g1b, drops, hs1);
  gemm_mfma<64, 0, 256, 0><<<GB, 512, 0, stream>>>(hs1, nullptr, WpG2, nullptr, nullptr,
                                                   nullptr, fsfd, nullptr);
  gat_fused<false><<<N_ / 4, 256, 0, stream>>>(fsfd, rowptr, colsrc, g2a, g2b, nullptr, out_s);
}

// Round 14
// 244.871 us; speedup vs baseline: 1.1120x; 1.1120x over previous
//
#include <hip/hip_runtime.h>
#include <math.h>

constexpr int N_  = 50000;
constexpr int E_  = 500000;
constexpr int NB_ = (N_ + 255) / 256;   // 196 scan blocks
constexpr int GB_  = (N_ + 63) / 64;    // 782 gemm blocks
constexpr int NGB_ = N_ / 4;            // 12500 gather blocks
constexpr int DEGB_ = (E_ + 255) / 256; // 1954
constexpr int PFB_  = N_ * 128 / 4 / 256; // 6250
constexpr int CSRB_ = (E_ + 511) / 512;   // 977

typedef unsigned short u16;
typedef unsigned int u32;
typedef short short8 __attribute__((ext_vector_type(8)));
typedef __bf16 bf16x8 __attribute__((ext_vector_type(8)));
typedef float f32x4 __attribute__((ext_vector_type(4)));
typedef short short4v __attribute__((ext_vector_type(4)));

#define DINL __device__ __forceinline__

DINL float gelu_f(float x) { return 0.5f * x * (1.f + erff(x * 0.70710678118654752f)); }
DINL float sigmoid_f(float x) { return 1.f / (1.f + expf(-x)); }
DINL u16 f2b(float x) {
  unsigned u = __float_as_uint(x);
  return (u16)((u + 0x7FFFu + ((u >> 16) & 1u)) >> 16);
}
DINL float b2f(u16 b) { return __uint_as_float(((unsigned)b) << 16); }

template <int CTRL>
DINL float dpp_add(float c) {
  int p = __builtin_amdgcn_update_dpp(0, __builtin_bit_cast(int, c), CTRL, 0xf, 0xf, false);
  return c + __builtin_bit_cast(float, p);
}
DINL float reduce16(float c) {
  c = dpp_add<0xB1>(c);
  c = dpp_add<0x4E>(c);
  c = dpp_add<0x141>(c);
  c = dpp_add<0x140>(c);
  return c;
}

// ================= scan =================
__global__ __launch_bounds__(256) void scan_local(const int* __restrict__ deg,
    int* __restrict__ rowptr, int* __restrict__ bsum) {
  __shared__ int sums[4];
  const int tid = threadIdx.x, lane = tid & 63, wid = tid >> 6;
  const int i = blockIdx.x * 256 + tid;
  int v = (i < N_) ? deg[i] : 0;
  int x = v;
#pragma unroll
  for (int o = 1; o < 64; o <<= 1) { int y = __shfl_up(x, o); if (lane >= o) x += y; }
  if (lane == 63) sums[wid] = x;
  __syncthreads();
  int woff = 0;
#pragma unroll
  for (int w = 0; w < 3; ++w) if (w < wid) woff += sums[w];
  if (i < N_) rowptr[i] = x - v + woff;
  if (tid == 255) bsum[blockIdx.x] = woff + x;
}

__global__ __launch_bounds__(256) void scan_block(const int* __restrict__ bsum,
                                                  int* __restrict__ bpre) {
  __shared__ int sums[4];
  const int tid = threadIdx.x, lane = tid & 63, wid = tid >> 6;
  int v = (tid < NB_) ? bsum[tid] : 0;
  int x = v;
#pragma unroll
  for (int o = 1; o < 64; o <<= 1) { int y = __shfl_up(x, o); if (lane >= o) x += y; }
  if (lane == 63) sums[wid] = x;
  __syncthreads();
  int woff = 0;
#pragma unroll
  for (int w = 0; w < 3; ++w) if (w < wid) woff += sums[w];
  if (tid < NB_) bpre[tid] = x - v + woff;
  if (tid == 255) bpre[NB_] = woff + x;
}

__global__ __launch_bounds__(256) void scan_add(int* __restrict__ rowptr,
                                                const int* __restrict__ bpre) {
  int i = blockIdx.x * 256 + threadIdx.x;
  if (i < N_) rowptr[i] += bpre[i >> 8];
  else if (i == N_) rowptr[N_] = bpre[NB_];
}

// ================= prep: degree + pack_feat + pack_w in one launch ==============
__global__ __launch_bounds__(256) void prep_kernel(
    const int* __restrict__ edst, int* __restrict__ degi,
    const float* __restrict__ feat, u16* __restrict__ featbf,
    const float* __restrict__ Wmt, const float* __restrict__ Wms,
    const float* __restrict__ W1s, const float* __restrict__ W1n,
    const float* __restrict__ W2s, const float* __restrict__ W2n,
    const float* __restrict__ g1Ws, const float* __restrict__ g1Wd,
    const float* __restrict__ g2Ws, const float* __restrict__ g2Wd,
    const float* __restrict__ W3, u16* __restrict__ Wpk) {
  int b = blockIdx.x, tid = threadIdx.x;
  if (b < DEGB_) {
    int t = b * 256 + tid;
    if (t < E_) atomicAdd(&degi[edst[t]], 1);
  } else if (b < DEGB_ + PFB_) {
    int t = (b - DEGB_) * 256 + tid;
    float4 v = ((const float4*)feat)[t];
    short4v r;
    r[0] = (short)f2b(v.x); r[1] = (short)f2b(v.y);
    r[2] = (short)f2b(v.z); r[3] = (short)f2b(v.w);
    ((short4v*)featbf)[t] = r;
  } else {
    int e = (b - DEGB_ - PFB_) * 256 + tid;
    const float *Wa, *Wb = nullptr;
    int K1, Ca, Cb = 0, st;
    if (e < 16384)       { Wa = Wmt;  K1 = 128; Ca = 128;           st = 0; }
    else if (e < 32768)  { Wa = Wms;  K1 = 128; Ca = 128;           st = 16384; }
    else if (e < 49152)  { Wa = W1s;  Wb = W1n; K1 = 128; Ca = 64; Cb = 64; st = 32768; }
    else if (e < 57344)  { Wa = W2s;  Wb = W2n; K1 = 64;  Ca = 64; Cb = 64; st = 49152; }
    else if (e < 90112)  { Wa = g1Ws; Wb = g1Wd; K1 = 128; Ca = 128; Cb = 128; st = 57344; }
    else if (e < 106496) { Wa = g2Ws; Wb = g2Wd; K1 = 64;  Ca = 128; Cb = 128; st = 90112; }
    else                 { Wa = W3;   K1 = 192; Ca = 64;            st = 106496; }
    int el = e - st;
    int ct = el / (K1 * 16);
    int rem = el - ct * K1 * 16;
    int ks = rem >> 9, rem2 = rem & 511, lane = rem2 >> 3, j = rem2 & 7;
    int k = ks * 32 + ((lane >> 4) << 3) + j;
    int c = ct * 16 + (lane & 15);
    float v = (c < Ca) ? Wa[k * Ca + c] : Wb[k * Cb + (c - Ca)];
    Wpk[e] = f2b(v);
  }
}

// ================= GEMM body (device function; EPI 0 = plain, 5 = dual-mask) =====
template <int K1, int K2, int C, int EPI>
DINL void gemm_body(int bid, u16* alds,
    const u16* __restrict__ A1, const u16* __restrict__ A2,
    const u16* __restrict__ Wp, const float* __restrict__ bias,
    const float* __restrict__ bias2, void* __restrict__ outv,
    void* __restrict__ outv2) {
  constexpr int K = K1 + K2, KS = K / 32, CT4 = C / 64;
  constexpr int NCH1 = K1 / 8, NCH2 = K2 / 8;
  const int tid = threadIdx.x;
  const int w = tid >> 6, l = tid & 63;
  const int cq = w >> 1, rh = w & 1;
  const int wr0 = bid * 64;

  short8 wfrag[KS][CT4];
#pragma unroll
  for (int ks = 0; ks < KS; ++ks)
#pragma unroll
    for (int c4 = 0; c4 < CT4; ++c4)
      wfrag[ks][c4] = *(const short8*)(Wp +
          ((size_t)((cq * CT4 + c4) * KS + ks) * 64 + l) * 8);

  for (int i = tid; i < 64 * NCH1; i += 512) {
    int rr = i / NCH1, kc = i % NCH1;
    int gr = wr0 + rr; if (gr >= N_) gr = N_ - 1;
    short8 v = *(const short8*)(A1 + (long)gr * K1 + kc * 8);
    *(short8*)&alds[rr * K + ((kc ^ (rr & 7)) << 3)] = v;
  }
  if constexpr (K2 > 0) {
    for (int i = tid; i < 64 * NCH2; i += 512) {
      int rr = i / NCH2, kc = i % NCH2;
      int gr = wr0 + rr; if (gr >= N_) gr = N_ - 1;
      short8 v = *(const short8*)(A2 + (long)gr * K2 + kc * 8);
      *(short8*)&alds[rr * K + (((NCH1 + kc) ^ (rr & 7)) << 3)] = v;
    }
  }
  __syncthreads();

  f32x4 acc[2][CT4];
#pragma unroll
  for (int rr = 0; rr < 2; ++rr)
#pragma unroll
    for (int c4 = 0; c4 < CT4; ++c4) acc[rr][c4] = (f32x4){0.f, 0.f, 0.f, 0.f};

#pragma unroll
  for (int ks = 0; ks < KS; ++ks) {
#pragma unroll
    for (int rr = 0; rr < 2; ++rr) {
      const int nr = (rh * 2 + rr) * 16 + (l & 15);
      const int ch = (ks * 4 + (l >> 4)) ^ (nr & 7);
      short8 av = *(const short8*)&alds[nr * K + (ch << 3)];
      bf16x8 bf = __builtin_bit_cast(bf16x8, av);
#pragma unroll
      for (int c4 = 0; c4 < CT4; ++c4)
        acc[rr][c4] = __builtin_amdgcn_mfma_f32_16x16x32_bf16(
            __builtin_bit_cast(bf16x8, wfrag[ks][c4]), bf, acc[rr][c4], 0, 0, 0);
    }
  }

  const int colq = (l >> 4) << 2;
  if constexpr (EPI == 0) {
    u16* out = (u16*)outv;
#pragma unroll
    for (int rr = 0; rr < 2; ++rr) {
      int row = wr0 + (rh * 2 + rr) * 16 + (l & 15);
      if (row >= N_) continue;
#pragma unroll
      for (int c4 = 0; c4 < CT4; ++c4) {
        int colb = (cq * CT4 + c4) * 16 + colq;
        short4v s;
#pragma unroll
        for (int r = 0; r < 4; ++r) s[r] = (short)f2b(acc[rr][c4][r]);
        *(short4v*)(out + (long)row * C + colb) = s;
      }
    }
  } else {                                  // EPI == 5: dual mask (C=256, K=128)
#pragma unroll
    for (int c4 = 0; c4 < CT4; ++c4) {
      const int ct = cq * CT4 + c4;
      const bool lo = ct < 8;
      u16* op = lo ? (u16*)outv : (u16*)outv2;
      const int ccb = (ct & 7) * 16 + colq;
      float4 bv = *(const float4*)((lo ? bias : bias2) + ccb);
#pragma unroll
      for (int rr = 0; rr < 2; ++rr) {
        int nl = (rh * 2 + rr) * 16 + (l & 15);
        int row = wr0 + nl;
        if (row >= N_) continue;
        int ch = (ccb >> 3) ^ (nl & 7);
        short4v fq = *(const short4v*)&alds[nl * K + (ch << 3) + (ccb & 7)];
        short4v s;
#pragma unroll
        for (int r = 0; r < 4; ++r) {
          float x = acc[rr][c4][r] + ((const float*)&bv)[r];
          float fv = b2f((u16)fq[r]);
          s[r] = (short)f2b(fv * sigmoid_f(x));
        }
        *(short4v*)(op + (long)row * 128 + ccb) = s;
      }
    }
  }
}

// ================= stage0: mask GEMM (EPI5) || csr_fill ==========================
__global__ __launch_bounds__(512) void stage0(
    const u16* __restrict__ featbf, const u16* __restrict__ WpMT,
    const float* __restrict__ bmt, const float* __restrict__ bms,
    u16* __restrict__ hbuf_t, u16* __restrict__ hbuf_s,
    const int* __restrict__ esrc, const int* __restrict__ edst,
    const int* __restrict__ rowptr, int* __restrict__ cursor,
    int* __restrict__ colsrc) {
  __shared__ u16 alds[64 * 128];
  int b = blockIdx.x;
  if (b < GB_) {
    gemm_body<128, 0, 256, 5>(b, alds, featbf, nullptr, WpMT, bmt, bms, hbuf_t, hbuf_s);
  } else {
    int e = (b - GB_) * 512 + threadIdx.x;
    if (e < E_) {
      int d = edst[e];
      int pos = rowptr[d] + atomicAdd(&cursor[d], 1);
      colsrc[pos] = esrc[e];
    }
  }
}

// ================= gemm pair stages (EPI0 x2) ====================================
template <int KA, int KB>
__global__ __launch_bounds__(512) void gemm_pair(
    const u16* __restrict__ A_a, const u16* __restrict__ Wp_a, u16* __restrict__ out_a,
    const u16* __restrict__ A_b, const u16* __restrict__ Wp_b, u16* __restrict__ out_b) {
  __shared__ u16 alds[64 * 128];
  int b = blockIdx.x;
  if (b < GB_) gemm_body<KA, 0, 128, 0>(b, alds, A_a, nullptr, Wp_a, nullptr, nullptr, out_a, nullptr);
  else         gemm_body<KB, 0, 256, 0>(b - GB_, alds, A_b, nullptr, Wp_b, nullptr, nullptr, out_b, nullptr);
}

// ================= final topology GEMM (EPI4, standalone) ========================
__global__ __launch_bounds__(512) void final_t(
    const u16* __restrict__ A1, const u16* __restrict__ A2,
    const u16* __restrict__ Wp, const float* __restrict__ bias,
    float* __restrict__ out) {
  constexpr int K1 = 64, K2 = 128, K = 192, KS = 6;
  constexpr int NCH1 = 8, NCH2 = 16;
  __shared__ u16 alds[64 * K];
  __shared__ float ssb[64][4];
  const int tid = threadIdx.x;
  const int w = tid >> 6, l = tid & 63;
  const int cq = w >> 1, rh = w & 1;
  const int wr0 = blockIdx.x * 64;

  short8 wfrag[KS];
#pragma unroll
  for (int ks = 0; ks < KS; ++ks)
    wfrag[ks] = *(const short8*)(Wp + ((size_t)(cq * KS + ks) * 64 + l) * 8);

  for (int i = tid; i < 64 * NCH1; i += 512) {
    int rr = i / NCH1, kc = i % NCH1;
    int gr = wr0 + rr; if (gr >= N_) gr = N_ - 1;
    short8 v = *(const short8*)(A1 + (long)gr * K1 + kc * 8);
    *(short8*)&alds[rr * K + ((kc ^ (rr & 7)) << 3)] = v;
  }
  for (int i = tid; i < 64 * NCH2; i += 512) {
    int rr = i / NCH2, kc = i % NCH2;
    int gr = wr0 + rr; if (gr >= N_) gr = N_ - 1;
    short8 v = *(const short8*)(A2 + (long)gr * K2 + kc * 8);
    *(short8*)&alds[rr * K + (((NCH1 + kc) ^ (rr & 7)) << 3)] = v;
  }
  __syncthreads();

  f32x4 acc[2];
  acc[0] = (f32x4){0.f, 0.f, 0.f, 0.f};
  acc[1] = (f32x4){0.f, 0.f, 0.f, 0.f};
#pragma unroll
  for (int ks = 0; ks < KS; ++ks) {
#pragma unroll
    for (int rr = 0; rr < 2; ++rr) {
      const int nr = (rh * 2 + rr) * 16 + (l & 15);
      const int ch = (ks * 4 + (l >> 4)) ^ (nr & 7);
      short8 av = *(const short8*)&alds[nr * K + (ch << 3)];
      acc[rr] = __builtin_amdgcn_mfma_f32_16x16x32_bf16(
          __builtin_bit_cast(bf16x8, wfrag[ks]),
          __builtin_bit_cast(bf16x8, av), acc[rr], 0, 0, 0);
    }
  }

  const int colq = (l >> 4) << 2;
  const int colb = cq * 16 + colq;
  float4 bv = *(const float4*)(bias + colb);
  float xv[2][4];
#pragma unroll
  for (int rr = 0; rr < 2; ++rr) {
    float ss = 0.f;
#pragma unroll
    for (int r = 0; r < 4; ++r) {
      float x = acc[rr][r] + ((const float*)&bv)[r];
      x = fmaxf(x, 0.01f * x);
      xv[rr][r] = x; ss += x * x;
    }
    ss += __shfl_xor(ss, 16);
    ss += __shfl_xor(ss, 32);
    if (l < 16) ssb[(rh * 2 + rr) * 16 + l][cq] = ss;
  }
  __syncthreads();
#pragma unroll
  for (int rr = 0; rr < 2; ++rr) {
    int nl = (rh * 2 + rr) * 16 + (l & 15);
    int row = wr0 + nl;
    if (row >= N_) continue;
    float ss = ssb[nl][0] + ssb[nl][1] + ssb[nl][2] + ssb[nl][3];
    float sc = 1.f / fmaxf(sqrtf(ss), 1e-12f);
    float4 o;
#pragma unroll
    for (int r = 0; r < 4; ++r) ((float*)&o)[r] = xv[rr][r] * sc;
    *(float4*)(out + (long)row * 64 + colb) = o;
  }
}

// ================= gather bodies =================
template <bool DROP>
DINL void sage_body(int node, const u16* __restrict__ qp,
    const int* __restrict__ rowptr, const int* __restrict__ colsrc,
    const float* __restrict__ bias, const float* __restrict__ drop,
    u16* __restrict__ out) {
  int l = threadIdx.x & 63;
  int ql = l & 15, qg = l >> 4;
  int beg = rowptr[node], end = rowptr[node + 1];
  const int off = 4 * ql;
  float a0 = 0.f, a1 = 0.f, a2 = 0.f, a3 = 0.f;
  float b0 = 0.f, b1 = 0.f, b2 = 0.f, b3 = 0.f;
  int j = beg;
  for (; j + 8 <= end; j += 8) {
    int s0 = colsrc[j + qg], s1 = colsrc[j + 4 + qg];
    uint2 v0 = *(const uint2*)(qp + (size_t)s0 * 128 + 64 + off);
    uint2 v1 = *(const uint2*)(qp + (size_t)s1 * 128 + 64 + off);
    a0 += b2f((u16)(v0.x & 0xffffu));
    a1 += b2f((u16)(v0.x >> 16));
    a2 += b2f((u16)(v0.y & 0xffffu));
    a3 += b2f((u16)(v0.y >> 16));
    b0 += b2f((u16)(v1.x & 0xffffu));
    b1 += b2f((u16)(v1.x >> 16));
    b2 += b2f((u16)(v1.y & 0xffffu));
    b3 += b2f((u16)(v1.y >> 16));
  }
  for (; j < end; j += 4) {
    int idx = j + qg;
    bool valid = idx < end;
    int s = colsrc[valid ? idx : end - 1];
    uint2 v = *(const uint2*)(qp + (size_t)s * 128 + 64 + off);
    if (!valid) { v.x = 0; v.y = 0; }
    a0 += b2f((u16)(v.x & 0xffffu));
    a1 += b2f((u16)(v.x >> 16));
    a2 += b2f((u16)(v.y & 0xffffu));
    a3 += b2f((u16)(v.y >> 16));
  }
  a0 += b0; a1 += b1; a2 += b2; a3 += b3;
  a0 += __shfl_xor(a0, 32); a1 += __shfl_xor(a1, 32);
  a2 += __shfl_xor(a2, 32); a3 += __shfl_xor(a3, 32);
  a0 += __shfl_xor(a0, 16); a1 += __shfl_xor(a1, 16);
  a2 += __shfl_xor(a2, 16); a3 += __shfl_xor(a3, 16);
  if (l < 16) {
    float inv = 1.f / fmaxf((float)(end - beg), 1.f);
    uint2 qv = *(const uint2*)(qp + (size_t)node * 128 + off);
    float4 bv = *(const float4*)(bias + off);
    float g0 = gelu_f(b2f((u16)(qv.x & 0xffffu)) + a0 * inv + bv.x);
    float g1 = gelu_f(b2f((u16)(qv.x >> 16))     + a1 * inv + bv.y);
    float g2 = gelu_f(b2f((u16)(qv.y & 0xffffu)) + a2 * inv + bv.z);
    float g3 = gelu_f(b2f((u16)(qv.y >> 16))     + a3 * inv + bv.w);
    if constexpr (DROP) {
      float4 dv = *(const float4*)(drop + (long)node * 64 + off);
      g0 *= dv.x; g1 *= dv.y; g2 *= dv.z; g3 *= dv.w;
    }
    short4v s;
    s[0] = (short)f2b(g0); s[1] = (short)f2b(g1);
    s[2] = (short)f2b(g2); s[3] = (short)f2b(g3);
    *(short4v*)(out + (long)node * 64 + off) = s;
  }
}

template <bool LAYER1>
DINL void gat_body(int node, const u16* __restrict__ fsfd,
    const int* __restrict__ rowptr, const int* __restrict__ colsrc,
    const float* __restrict__ attn, const float* __restrict__ bias,
    const float* __restrict__ drop, void* __restrict__ outv) {
  int l = threadIdx.x & 63;
  int hl = l & 31, half = l >> 5;
  const int off = 4 * hl;
  float4 av = *(const float4*)(attn + off);
  uint2 fdv = *(const uint2*)(fsfd + (size_t)node * 256 + 128 + off);
  float fd0 = b2f((u16)(fdv.x & 0xffffu)), fd1 = b2f((u16)(fdv.x >> 16));
  float fd2 = b2f((u16)(fdv.y & 0xffffu)), fd3 = b2f((u16)(fdv.y >> 16));
  float d_own = 0.f, acc0 = 0.f, acc1 = 0.f, acc2 = 0.f, acc3 = 0.f;

  auto edge = [&](uint2 v, float m) {
    float f0 = b2f((u16)(v.x & 0xffffu)), f1 = b2f((u16)(v.x >> 16));
    float f2 = b2f((u16)(v.y & 0xffffu)), f3 = b2f((u16)(v.y >> 16));
    float t0 = f0 + fd0, t1 = f1 + fd1, t2 = f2 + fd2, t3 = f3 + fd3;
    t0 = fmaxf(t0, 0.2f * t0); t1 = fmaxf(t1, 0.2f * t1);
    t2 = fmaxf(t2, 0.2f * t2); t3 = fmaxf(t3, 0.2f * t3);
    float c = t0 * av.x + t1 * av.y + t2 * av.z + t3 * av.w;
    c = reduce16(c);
    float e = __expf(c) * m;
    d_own += e;
    acc0 += e * f0; acc1 += e * f1; acc2 += e * f2; acc3 += e * f3;
  };

  const int beg = rowptr[node], end = rowptr[node + 1];
  int j = beg;
  for (; j + 8 <= end; j += 8) {
    int sa = colsrc[j + half],     sb = colsrc[j + 2 + half];
    int sc = colsrc[j + 4 + half], sd = colsrc[j + 6 + half];
    uint2 va = *(const uint2*)(fsfd + (size_t)sa * 256 + off);
    uint2 vb = *(const uint2*)(fsfd + (size_t)sb * 256 + off);
    uint2 vc = *(const uint2*)(fsfd + (size_t)sc * 256 + off);
    uint2 vd = *(const uint2*)(fsfd + (size_t)sd * 256 + off);
    edge(va, 1.f); edge(vb, 1.f); edge(vc, 1.f); edge(vd, 1.f);
  }
  for (; j < end; j += 2) {
    int idx = j + half;
    bool valid = idx < end;
    int s = colsrc[valid ? idx : end - 1];
    uint2 v = *(const uint2*)(fsfd + (size_t)s * 256 + off);
    if (!valid) { v.x = 0; v.y = 0; }
    edge(v, valid ? 1.f : 0.f);
  }

  acc0 += __shfl_xor(acc0, 32); acc1 += __shfl_xor(acc1, 32);
  acc2 += __shfl_xor(acc2, 32); acc3 += __shfl_xor(acc3, 32);
  d_own += __shfl_xor(d_own, 32);

  float4 bv = *(const float4*)(bias + off);
  float inv = d_own > 0.f ? 1.f / d_own : 0.f;
  float g0 = gelu_f(bv.x + acc0 * inv);
  float g1 = gelu_f(bv.y + acc1 * inv);
  float g2 = gelu_f(bv.z + acc2 * inv);
  float g3 = gelu_f(bv.w + acc3 * inv);
  float v0 = 0.5f * (g0 + __shfl_xor(g0, 16));
  float v1 = 0.5f * (g1 + __shfl_xor(g1, 16));
  float v2 = 0.5f * (g2 + __shfl_xor(g2, 16));
  float v3 = 0.5f * (g3 + __shfl_xor(g3, 16));
  if constexpr (LAYER1) {
    if (l < 16) {
      float4 dv = *(const float4*)(drop + (long)node * 64 + 4 * l);
      short4v s;
      s[0] = (short)f2b(v0 * dv.x); s[1] = (short)f2b(v1 * dv.y);
      s[2] = (short)f2b(v2 * dv.z); s[3] = (short)f2b(v3 * dv.w);
      *(short4v*)((u16*)outv + (long)node * 64 + 4 * l) = s;
    }
  } else {
    float ss = v0 * v0 + v1 * v1 + v2 * v2 + v3 * v3;
    ss = reduce16(ss);
    float sc = 1.f / fmaxf(sqrtf(ss), 1e-12f);
    if (l < 16) {
      float4 o; o.x = v0 * sc; o.y = v1 * sc; o.z = v2 * sc; o.w = v3 * sc;
      *(float4*)((float*)outv + (long)node * 64 + 4 * l) = o;
    }
  }
}

// ================= merged gather stage: gat || sage ==============================
template <bool LAYER1, bool DROP>
__global__ __launch_bounds__(256) void gather_stage(
    const u16* __restrict__ fsfd, const u16* __restrict__ qp,
    const int* __restrict__ rowptr, const int* __restrict__ colsrc,
    const float* __restrict__ attn, const float* __restrict__ gbias,
    const float* __restrict__ sbias, const float* __restrict__ gdrop,
    const float* __restrict__ sdrop, void* __restrict__ gout,
    u16* __restrict__ sout) {
  int b = blockIdx.x;
  if (b < NGB_) {
    int node = b * 4 + (threadIdx.x >> 6);
    gat_body<LAYER1>(node, fsfd, rowptr, colsrc, attn, gbias, gdrop, gout);
  } else {
    int node = (b - NGB_) * 4 + (threadIdx.x >> 6);
    sage_body<DROP>(node, qp, rowptr, colsrc, sbias, sdrop, sout);
  }
}

extern "C" void kernel_launch(void* const* d_in, const int* in_sizes, int n_in,
                              void* d_out, int out_size, void* d_ws, size_t ws_size,
                              hipStream_t stream) {
  const float* feat = (const float*)d_in[0];
  const int*   esrc = (const int*)d_in[1];
  const int*   edst = (const int*)d_in[2];
  const float* Wmt = (const float*)d_in[3],  *bmt = (const float*)d_in[4];
  const float* Wms = (const float*)d_in[5],  *bms = (const float*)d_in[6];
  const float* W1s = (const float*)d_in[7],  *W1n = (const float*)d_in[8],  *b1 = (const float*)d_in[9];
  const float* W2s = (const float*)d_in[10], *W2n = (const float*)d_in[11], *b2 = (const float*)d_in[12];
  const float* g1Ws = (const float*)d_in[13], *g1Wd = (const float*)d_in[14];
  const float* g1a  = (const float*)d_in[15], *g1b  = (const float*)d_in[16];
  const float* g2Ws = (const float*)d_in[17], *g2Wd = (const float*)d_in[18];
  const float* g2a  = (const float*)d_in[19], *g2b  = (const float*)d_in[20];
  const float* W3  = (const float*)d_in[21], *b3 = (const float*)d_in[22];
  const float* dropt = (const float*)d_in[23], *drops = (const float*)d_in[24];

  float* out_t = (float*)d_out;
  float* out_s = out_t + (long)N_ * 64;

  // workspace (u16 units)
  u16* wsh = (u16*)d_ws;
  u16* featbf = wsh;                 // N*128
  u16* hbuf_t = wsh +  6400000;      // N*128
  u16* hbuf_s = wsh + 12800000;      // N*128
  u16* qp1    = wsh + 19200000;      // N*128  [q1|p1]
  u16* h1     = wsh + 25600000;      // N*64
  u16* qp2    = wsh + 28800000;      // N*128  [q2|p2]
  u16* h2     = wsh + 35200000;      // N*64
  u16* hs1    = wsh + 38400000;      // N*64
  u16* fsfd   = wsh + 41600000;      // N*256
  u16* Wpk    = wsh + 54400000;      // 118784
  int* degi   = (int*)(wsh + 54518784);  // N
  int* cursor = degi + N_;               // N
  int* rowptr = cursor + N_;             // N+1
  int* colsrc = rowptr + N_ + 1;         // E
  int* bsum   = colsrc + E_;             // NB_
  int* bpre   = bsum + NB_;              // NB_+1

  const u16* WpMT = Wpk;             // [Wmt|Wms]
  const u16* WpS1 = Wpk + 32768;     // [W1s|W1n] C-concat
  const u16* WpS2 = Wpk + 49152;     // [W2s|W2n] C-concat
  const u16* WpG1 = Wpk + 57344;
  const u16* WpG2 = Wpk + 90112;
  const u16* WpW3 = Wpk + 106496;

  // ---- prep: degree + packs (one launch) ----
  (void)hipMemsetAsync(degi, 0, (size_t)(2 * N_) * sizeof(int), stream);
  prep_kernel<<<DEGB_ + PFB_ + 464, 256, 0, stream>>>(edst, degi, feat, featbf,
      Wmt, Wms, W1s, W1n, W2s, W2n, g1Ws, g1Wd, g2Ws, g2Wd, W3, Wpk);
  scan_local<<<NB_, 256, 0, stream>>>(degi, rowptr, bsum);
  scan_block<<<1, 256, 0, stream>>>(bsum, bpre);
  scan_add<<<(N_ + 256) / 256, 256, 0, stream>>>(rowptr, bpre);

  // ---- stage0: mask GEMM || csr_fill ----
  stage0<<<GB_ + CSRB_, 512, 0, stream>>>(featbf, WpMT, bmt, bms, hbuf_t, hbuf_s,
                                          esrc, edst, rowptr, cursor, colsrc);

  // ---- stage1: S1 GEMM || G1 GEMM ----
  gemm_pair<128, 128><<<2 * GB_, 512, 0, stream>>>(hbuf_t, WpS1, qp1,
                                                   hbuf_s, WpG1, fsfd);
  // ---- stage2: gat1 || gather_sage1 ----
  gather_stage<true, true><<<2 * NGB_, 256, 0, stream>>>(fsfd, qp1, rowptr, colsrc,
      g1a, g1b, b1, drops, dropt, hs1, h1);
  // ---- stage3: S2 GEMM || G2 GEMM ----
  gemm_pair<64, 64><<<2 * GB_, 512, 0, stream>>>(h1, WpS2, qp2,
                                                 hs1, WpG2, fsfd);
  // ---- stage4: gat2 || gather_sage2 ----
  gather_stage<false, false><<<2 * NGB_, 256, 0, stream>>>(fsfd, qp2, rowptr, colsrc,
      g2a, g2b, b2, nullptr, nullptr, out_s, h2);
  // ---- final topology GEMM ----
  final_t<<<GB_, 512, 0, stream>>>(h2, featbf, WpW3, b3, out_t);
}

// Round 15
// 230.115 us; speedup vs baseline: 1.1833x; 1.0641x over previous
//
#include <hip/hip_runtime.h>
#include <math.h>

constexpr int N_  = 50000;
constexpr int E_  = 500000;
constexpr int NB_ = (N_ + 255) / 256;   // 196 scan blocks
constexpr int GB_  = (N_ + 63) / 64;    // 782 gemm blocks
constexpr int NGB_ = N_ / 4;            // 12500 gather blocks
constexpr int DEGB_ = (E_ + 255) / 256; // 1954
constexpr int PFB_  = N_ * 128 / 4 / 256; // 6250
constexpr int CSRB_ = (E_ + 511) / 512;   // 977

typedef unsigned short u16;
typedef unsigned char u8;
typedef unsigned int u32;
typedef short short8 __attribute__((ext_vector_type(8)));
typedef __bf16 bf16x8 __attribute__((ext_vector_type(8)));
typedef float f32x4 __attribute__((ext_vector_type(4)));
typedef float f32x2 __attribute__((ext_vector_type(2)));
typedef short short4v __attribute__((ext_vector_type(4)));

#define DINL __device__ __forceinline__

DINL float gelu_f(float x) { return 0.5f * x * (1.f + erff(x * 0.70710678118654752f)); }
DINL float sigmoid_f(float x) { return 1.f / (1.f + expf(-x)); }
DINL u16 f2b(float x) {
  unsigned u = __float_as_uint(x);
  return (u16)((u + 0x7FFFu + ((u >> 16) & 1u)) >> 16);
}
DINL float b2f(u16 b) { return __uint_as_float(((unsigned)b) << 16); }
DINL u32 pk_fp8x4(float a, float b, float c, float d) {
  int w = __builtin_amdgcn_cvt_pk_fp8_f32(a, b, 0, false);
  w = __builtin_amdgcn_cvt_pk_fp8_f32(c, d, w, true);
  return (u32)w;
}

template <int CTRL>
DINL float dpp_add(float c) {
  int p = __builtin_amdgcn_update_dpp(0, __builtin_bit_cast(int, c), CTRL, 0xf, 0xf, false);
  return c + __builtin_bit_cast(float, p);
}
DINL float reduce16(float c) {
  c = dpp_add<0xB1>(c);
  c = dpp_add<0x4E>(c);
  c = dpp_add<0x141>(c);
  c = dpp_add<0x140>(c);
  return c;
}

// ================= scan =================
__global__ __launch_bounds__(256) void scan_local(const int* __restrict__ deg,
    int* __restrict__ rowptr, int* __restrict__ bsum) {
  __shared__ int sums[4];
  const int tid = threadIdx.x, lane = tid & 63, wid = tid >> 6;
  const int i = blockIdx.x * 256 + tid;
  int v = (i < N_) ? deg[i] : 0;
  int x = v;
#pragma unroll
  for (int o = 1; o < 64; o <<= 1) { int y = __shfl_up(x, o); if (lane >= o) x += y; }
  if (lane == 63) sums[wid] = x;
  __syncthreads();
  int woff = 0;
#pragma unroll
  for (int w = 0; w < 3; ++w) if (w < wid) woff += sums[w];
  if (i < N_) rowptr[i] = x - v + woff;
  if (tid == 255) bsum[blockIdx.x] = woff + x;
}

__global__ __launch_bounds__(256) void scan_block(const int* __restrict__ bsum,
                                                  int* __restrict__ bpre) {
  __shared__ int sums[4];
  const int tid = threadIdx.x, lane = tid & 63, wid = tid >> 6;
  int v = (tid < NB_) ? bsum[tid] : 0;
  int x = v;
#pragma unroll
  for (int o = 1; o < 64; o <<= 1) { int y = __shfl_up(x, o); if (lane >= o) x += y; }
  if (lane == 63) sums[wid] = x;
  __syncthreads();
  int woff = 0;
#pragma unroll
  for (int w = 0; w < 3; ++w) if (w < wid) woff += sums[w];
  if (tid < NB_) bpre[tid] = x - v + woff;
  if (tid == 255) bpre[NB_] = woff + x;
}

__global__ __launch_bounds__(256) void scan_add(int* __restrict__ rowptr,
                                                const int* __restrict__ bpre) {
  int i = blockIdx.x * 256 + threadIdx.x;
  if (i < N_) rowptr[i] += bpre[i >> 8];
  else if (i == N_) rowptr[N_] = bpre[NB_];
}

// ================= prep: degree + pack_feat + pack_w ==============
__global__ __launch_bounds__(256) void prep_kernel(
    const int* __restrict__ edst, int* __restrict__ degi,
    const float* __restrict__ feat, u16* __restrict__ featbf,
    const float* __restrict__ Wmt, const float* __restrict__ Wms,
    const float* __restrict__ W1s, const float* __restrict__ W1n,
    const float* __restrict__ W2s, const float* __restrict__ W2n,
    const float* __restrict__ g1Ws, const float* __restrict__ g1Wd,
    const float* __restrict__ g2Ws, const float* __restrict__ g2Wd,
    const float* __restrict__ W3, u16* __restrict__ Wpk) {
  int b = blockIdx.x, tid = threadIdx.x;
  if (b < DEGB_) {
    int t = b * 256 + tid;
    if (t < E_) atomicAdd(&degi[edst[t]], 1);
  } else if (b < DEGB_ + PFB_) {
    int t = (b - DEGB_) * 256 + tid;
    float4 v = ((const float4*)feat)[t];
    short4v r;
    r[0] = (short)f2b(v.x); r[1] = (short)f2b(v.y);
    r[2] = (short)f2b(v.z); r[3] = (short)f2b(v.w);
    ((short4v*)featbf)[t] = r;
  } else {
    int e = (b - DEGB_ - PFB_) * 256 + tid;
    const float *Wa, *Wb = nullptr;
    int K1, Ca, Cb = 0, st;
    if (e < 16384)       { Wa = Wmt;  K1 = 128; Ca = 128;           st = 0; }
    else if (e < 32768)  { Wa = Wms;  K1 = 128; Ca = 128;           st = 16384; }
    else if (e < 49152)  { Wa = W1s;  Wb = W1n; K1 = 128; Ca = 64; Cb = 64; st = 32768; }
    else if (e < 57344)  { Wa = W2s;  Wb = W2n; K1 = 64;  Ca = 64; Cb = 64; st = 49152; }
    else if (e < 90112)  { Wa = g1Ws; Wb = g1Wd; K1 = 128; Ca = 128; Cb = 128; st = 57344; }
    else if (e < 106496) { Wa = g2Ws; Wb = g2Wd; K1 = 64;  Ca = 128; Cb = 128; st = 90112; }
    else                 { Wa = W3;   K1 = 192; Ca = 64;            st = 106496; }
    int el = e - st;
    int ct = el / (K1 * 16);
    int rem = el - ct * K1 * 16;
    int ks = rem >> 9, rem2 = rem & 511, lane = rem2 >> 3, j = rem2 & 7;
    int k = ks * 32 + ((lane >> 4) << 3) + j;
    int c = ct * 16 + (lane & 15);
    float v = (c < Ca) ? Wa[k * Ca + c] : Wb[k * Cb + (c - Ca)];
    Wpk[e] = f2b(v);
  }
}

// ================= GEMM body =================
// EPI 5: dual-mask bf16x2 (C=256); EPI 6: fp8 out (C=256, for GAT fs/fd);
// EPI 7: split q(bf16)/p(fp8) (C=128, for SAGE)
template <int K1, int K2, int C, int EPI>
DINL void gemm_body(int bid, u16* alds,
    const u16* __restrict__ A1, const u16* __restrict__ A2,
    const u16* __restrict__ Wp, const float* __restrict__ bias,
    const float* __restrict__ bias2, void* __restrict__ outv,
    void* __restrict__ outv2) {
  constexpr int K = K1 + K2, KS = K / 32, CT4 = C / 64;
  constexpr int NCH1 = K1 / 8, NCH2 = K2 / 8;
  const int tid = threadIdx.x;
  const int w = tid >> 6, l = tid & 63;
  const int cq = w >> 1, rh = w & 1;
  const int wr0 = bid * 64;

  short8 wfrag[KS][CT4];
#pragma unroll
  for (int ks = 0; ks < KS; ++ks)
#pragma unroll
    for (int c4 = 0; c4 < CT4; ++c4)
      wfrag[ks][c4] = *(const short8*)(Wp +
          ((size_t)((cq * CT4 + c4) * KS + ks) * 64 + l) * 8);

  for (int i = tid; i < 64 * NCH1; i += 512) {
    int rr = i / NCH1, kc = i % NCH1;
    int gr = wr0 + rr; if (gr >= N_) gr = N_ - 1;
    short8 v = *(const short8*)(A1 + (long)gr * K1 + kc * 8);
    *(short8*)&alds[rr * K + ((kc ^ (rr & 7)) << 3)] = v;
  }
  if constexpr (K2 > 0) {
    for (int i = tid; i < 64 * NCH2; i += 512) {
      int rr = i / NCH2, kc = i % NCH2;
      int gr = wr0 + rr; if (gr >= N_) gr = N_ - 1;
      short8 v = *(const short8*)(A2 + (long)gr * K2 + kc * 8);
      *(short8*)&alds[rr * K + (((NCH1 + kc) ^ (rr & 7)) << 3)] = v;
    }
  }
  __syncthreads();

  f32x4 acc[2][CT4];
#pragma unroll
  for (int rr = 0; rr < 2; ++rr)
#pragma unroll
    for (int c4 = 0; c4 < CT4; ++c4) acc[rr][c4] = (f32x4){0.f, 0.f, 0.f, 0.f};

#pragma unroll
  for (int ks = 0; ks < KS; ++ks) {
#pragma unroll
    for (int rr = 0; rr < 2; ++rr) {
      const int nr = (rh * 2 + rr) * 16 + (l & 15);
      const int ch = (ks * 4 + (l >> 4)) ^ (nr & 7);
      short8 av = *(const short8*)&alds[nr * K + (ch << 3)];
      bf16x8 bf = __builtin_bit_cast(bf16x8, av);
#pragma unroll
      for (int c4 = 0; c4 < CT4; ++c4)
        acc[rr][c4] = __builtin_amdgcn_mfma_f32_16x16x32_bf16(
            __builtin_bit_cast(bf16x8, wfrag[ks][c4]), bf, acc[rr][c4], 0, 0, 0);
    }
  }

  const int colq = (l >> 4) << 2;
  if constexpr (EPI == 5) {                 // dual mask (C=256, K=128)
#pragma unroll
    for (int c4 = 0; c4 < CT4; ++c4) {
      const int ct = cq * CT4 + c4;
      const bool lo = ct < 8;
      u16* op = lo ? (u16*)outv : (u16*)outv2;
      const int ccb = (ct & 7) * 16 + colq;
      float4 bv = *(const float4*)((lo ? bias : bias2) + ccb);
#pragma unroll
      for (int rr = 0; rr < 2; ++rr) {
        int nl = (rh * 2 + rr) * 16 + (l & 15);
        int row = wr0 + nl;
        if (row >= N_) continue;
        int ch = (ccb >> 3) ^ (nl & 7);
        short4v fq = *(const short4v*)&alds[nl * K + (ch << 3) + (ccb & 7)];
        short4v s;
#pragma unroll
        for (int r = 0; r < 4; ++r) {
          float x = acc[rr][c4][r] + ((const float*)&bv)[r];
          float fv = b2f((u16)fq[r]);
          s[r] = (short)f2b(fv * sigmoid_f(x));
        }
        *(short4v*)(op + (long)row * 128 + ccb) = s;
      }
    }
  } else if constexpr (EPI == 6) {          // fp8 out (C=256)
    u8* out = (u8*)outv;
#pragma unroll
    for (int rr = 0; rr < 2; ++rr) {
      int row = wr0 + (rh * 2 + rr) * 16 + (l & 15);
      if (row >= N_) continue;
#pragma unroll
      for (int c4 = 0; c4 < CT4; ++c4) {
        int colb = (cq * CT4 + c4) * 16 + colq;
        u32 wrd = pk_fp8x4(acc[rr][c4][0], acc[rr][c4][1],
                           acc[rr][c4][2], acc[rr][c4][3]);
        *(u32*)(out + (size_t)row * 256 + colb) = wrd;
      }
    }
  } else {                                  // EPI == 7: q bf16 / p fp8 (C=128)
    u16* qo = (u16*)outv;
    u8*  po = (u8*)outv2;
#pragma unroll
    for (int rr = 0; rr < 2; ++rr) {
      int row = wr0 + (rh * 2 + rr) * 16 + (l & 15);
      if (row >= N_) continue;
#pragma unroll
      for (int c4 = 0; c4 < CT4; ++c4) {
        int col = (cq * CT4 + c4) * 16 + colq;
        if (col < 64) {
          short4v s;
#pragma unroll
          for (int r = 0; r < 4; ++r) s[r] = (short)f2b(acc[rr][c4][r]);
          *(short4v*)(qo + (long)row * 64 + col) = s;
        } else {
          u32 wrd = pk_fp8x4(acc[rr][c4][0], acc[rr][c4][1],
                             acc[rr][c4][2], acc[rr][c4][3]);
          *(u32*)(po + (size_t)row * 64 + (col - 64)) = wrd;
        }
      }
    }
  }
}

// ================= stage0: mask GEMM (EPI5) || csr_fill ==========================
__global__ __launch_bounds__(512) void stage0(
    const u16* __restrict__ featbf, const u16* __restrict__ WpMT,
    const float* __restrict__ bmt, const float* __restrict__ bms,
    u16* __restrict__ hbuf_t, u16* __restrict__ hbuf_s,
    const int* __restrict__ esrc, const int* __restrict__ edst,
    const int* __restrict__ rowptr, int* __restrict__ cursor,
    int* __restrict__ colsrc) {
  __shared__ u16 alds[64 * 128];
  int b = blockIdx.x;
  if (b < GB_) {
    gemm_body<128, 0, 256, 5>(b, alds, featbf, nullptr, WpMT, bmt, bms, hbuf_t, hbuf_s);
  } else {
    int e = (b - GB_) * 512 + threadIdx.x;
    if (e < E_) {
      int d = edst[e];
      int pos = rowptr[d] + atomicAdd(&cursor[d], 1);
      colsrc[pos] = esrc[e];
    }
  }
}

// ================= gemm pair stages: SAGE(EPI7) || GAT(EPI6) =====================
template <int KA, int KB>
__global__ __launch_bounds__(512) void gemm_pair(
    const u16* __restrict__ A_a, const u16* __restrict__ Wp_a,
    u16* __restrict__ q_a, u8* __restrict__ p_a,
    const u16* __restrict__ A_b, const u16* __restrict__ Wp_b,
    u8* __restrict__ f8_b) {
  __shared__ u16 alds[64 * 128];
  int b = blockIdx.x;
  if (b < GB_) gemm_body<KA, 0, 128, 7>(b, alds, A_a, nullptr, Wp_a, nullptr, nullptr, q_a, p_a);
  else         gemm_body<KB, 0, 256, 6>(b - GB_, alds, A_b, nullptr, Wp_b, nullptr, nullptr, f8_b, nullptr);
}

// ================= final topology GEMM (leaky + l2norm) ==========================
__global__ __launch_bounds__(512) void final_t(
    const u16* __restrict__ A1, const u16* __restrict__ A2,
    const u16* __restrict__ Wp, const float* __restrict__ bias,
    float* __restrict__ out) {
  constexpr int K1 = 64, K2 = 128, K = 192, KS = 6;
  constexpr int NCH1 = 8, NCH2 = 16;
  __shared__ u16 alds[64 * K];
  __shared__ float ssb[64][4];
  const int tid = threadIdx.x;
  const int w = tid >> 6, l = tid & 63;
  const int cq = w >> 1, rh = w & 1;
  const int wr0 = blockIdx.x * 64;

  short8 wfrag[KS];
#pragma unroll
  for (int ks = 0; ks < KS; ++ks)
    wfrag[ks] = *(const short8*)(Wp + ((size_t)(cq * KS + ks) * 64 + l) * 8);

  for (int i = tid; i < 64 * NCH1; i += 512) {
    int rr = i / NCH1, kc = i % NCH1;
    int gr = wr0 + rr; if (gr >= N_) gr = N_ - 1;
    short8 v = *(const short8*)(A1 + (long)gr * K1 + kc * 8);
    *(short8*)&alds[rr * K + ((kc ^ (rr & 7)) << 3)] = v;
  }
  for (int i = tid; i < 64 * NCH2; i += 512) {
    int rr = i / NCH2, kc = i % NCH2;
    int gr = wr0 + rr; if (gr >= N_) gr = N_ - 1;
    short8 v = *(const short8*)(A2 + (long)gr * K2 + kc * 8);
    *(short8*)&alds[rr * K + (((NCH1 + kc) ^ (rr & 7)) << 3)] = v;
  }
  __syncthreads();

  f32x4 acc[2];
  acc[0] = (f32x4){0.f, 0.f, 0.f, 0.f};
  acc[1] = (f32x4){0.f, 0.f, 0.f, 0.f};
#pragma unroll
  for (int ks = 0; ks < KS; ++ks) {
#pragma unroll
    for (int rr = 0; rr < 2; ++rr) {
      const int nr = (rh * 2 + rr) * 16 + (l & 15);
      const int ch = (ks * 4 + (l >> 4)) ^ (nr & 7);
      short8 av = *(const short8*)&alds[nr * K + (ch << 3)];
      acc[rr] = __builtin_amdgcn_mfma_f32_16x16x32_bf16(
          __builtin_bit_cast(bf16x8, wfrag[ks]),
          __builtin_bit_cast(bf16x8, av), acc[rr], 0, 0, 0);
    }
  }

  const int colq = (l >> 4) << 2;
  const int colb = cq * 16 + colq;
  float4 bv = *(const float4*)(bias + colb);
  float xv[2][4];
#pragma unroll
  for (int rr = 0; rr < 2; ++rr) {
    float ss = 0.f;
#pragma unroll
    for (int r = 0; r < 4; ++r) {
      float x = acc[rr][r] + ((const float*)&bv)[r];
      x = fmaxf(x, 0.01f * x);
      xv[rr][r] = x; ss += x * x;
    }
    ss += __shfl_xor(ss, 16);
    ss += __shfl_xor(ss, 32);
    if (l < 16) ssb[(rh * 2 + rr) * 16 + l][cq] = ss;
  }
  __syncthreads();
#pragma unroll
  for (int rr = 0; rr < 2; ++rr) {
    int nl = (rh * 2 + rr) * 16 + (l & 15);
    int row = wr0 + nl;
    if (row >= N_) continue;
    float ss = ssb[nl][0] + ssb[nl][1] + ssb[nl][2] + ssb[nl][3];
    float sc = 1.f / fmaxf(sqrtf(ss), 1e-12f);
    float4 o;
#pragma unroll
    for (int r = 0; r < 4; ++r) ((float*)&o)[r] = xv[rr][r] * sc;
    *(float4*)(out + (long)row * 64 + colb) = o;
  }
}

// ================= gather bodies (fp8 tables) =================
template <bool DROP>
DINL void sage_body(int node, const u16* __restrict__ q, const u8* __restrict__ p,
    const int* __restrict__ rowptr, const int* __restrict__ colsrc,
    const float* __restrict__ bias, const float* __restrict__ drop,
    u16* __restrict__ out) {
  int l = threadIdx.x & 63;
  int ql = l & 15, qg = l >> 4;
  int beg = rowptr[node], end = rowptr[node + 1];
  const int off = 4 * ql;
  float a0 = 0.f, a1 = 0.f, a2 = 0.f, a3 = 0.f;
  float b0 = 0.f, b1 = 0.f, b2 = 0.f, b3 = 0.f;
  int j = beg;
  for (; j + 8 <= end; j += 8) {
    int s0 = colsrc[j + qg], s1 = colsrc[j + 4 + qg];
    u32 v0 = *(const u32*)(p + (size_t)s0 * 64 + off);
    u32 v1 = *(const u32*)(p + (size_t)s1 * 64 + off);
    f32x2 lo0 = __builtin_amdgcn_cvt_pk_f32_fp8((int)v0, false);
    f32x2 hi0 = __builtin_amdgcn_cvt_pk_f32_fp8((int)v0, true);
    f32x2 lo1 = __builtin_amdgcn_cvt_pk_f32_fp8((int)v1, false);
    f32x2 hi1 = __builtin_amdgcn_cvt_pk_f32_fp8((int)v1, true);
    a0 += lo0[0]; a1 += lo0[1]; a2 += hi0[0]; a3 += hi0[1];
    b0 += lo1[0]; b1 += lo1[1]; b2 += hi1[0]; b3 += hi1[1];
  }
  for (; j < end; j += 4) {
    int idx = j + qg;
    bool valid = idx < end;
    int s = colsrc[valid ? idx : end - 1];
    u32 v = *(const u32*)(p + (size_t)s * 64 + off);
    if (!valid) v = 0;
    f32x2 lo = __builtin_amdgcn_cvt_pk_f32_fp8((int)v, false);
    f32x2 hi = __builtin_amdgcn_cvt_pk_f32_fp8((int)v, true);
    a0 += lo[0]; a1 += lo[1]; a2 += hi[0]; a3 += hi[1];
  }
  a0 += b0; a1 += b1; a2 += b2; a3 += b3;
  a0 += __shfl_xor(a0, 32); a1 += __shfl_xor(a1, 32);
  a2 += __shfl_xor(a2, 32); a3 += __shfl_xor(a3, 32);
  a0 += __shfl_xor(a0, 16); a1 += __shfl_xor(a1, 16);
  a2 += __shfl_xor(a2, 16); a3 += __shfl_xor(a3, 16);
  if (l < 16) {
    float inv = 1.f / fmaxf((float)(end - beg), 1.f);
    uint2 qv = *(const uint2*)(q + (size_t)node * 64 + off);
    float4 bv = *(const float4*)(bias + off);
    float g0 = gelu_f(b2f((u16)(qv.x & 0xffffu)) + a0 * inv + bv.x);
    float g1 = gelu_f(b2f((u16)(qv.x >> 16))     + a1 * inv + bv.y);
    float g2 = gelu_f(b2f((u16)(qv.y & 0xffffu)) + a2 * inv + bv.z);
    float g3 = gelu_f(b2f((u16)(qv.y >> 16))     + a3 * inv + bv.w);
    if constexpr (DROP) {
      float4 dv = *(const float4*)(drop + (long)node * 64 + off);
      g0 *= dv.x; g1 *= dv.y; g2 *= dv.z; g3 *= dv.w;
    }
    short4v s;
    s[0] = (short)f2b(g0); s[1] = (short)f2b(g1);
    s[2] = (short)f2b(g2); s[3] = (short)f2b(g3);
    *(short4v*)(out + (long)node * 64 + off) = s;
  }
}

template <bool LAYER1>
DINL void gat_body(int node, const u8* __restrict__ fsfd,
    const int* __restrict__ rowptr, const int* __restrict__ colsrc,
    const float* __restrict__ attn, const float* __restrict__ bias,
    const float* __restrict__ drop, void* __restrict__ outv) {
  int l = threadIdx.x & 63;
  int hl = l & 31, half = l >> 5;
  const int off = 4 * hl;          // byte == col index (fp8)
  float4 av = *(const float4*)(attn + off);
  u32 fdw = *(const u32*)(fsfd + (size_t)node * 256 + 128 + off);
  f32x2 fdl = __builtin_amdgcn_cvt_pk_f32_fp8((int)fdw, false);
  f32x2 fdh = __builtin_amdgcn_cvt_pk_f32_fp8((int)fdw, true);
  float fd0 = fdl[0], fd1 = fdl[1], fd2 = fdh[0], fd3 = fdh[1];
  float d_own = 0.f, acc0 = 0.f, acc1 = 0.f, acc2 = 0.f, acc3 = 0.f;

  auto edge = [&](u32 v, float m) {
    f32x2 lo = __builtin_amdgcn_cvt_pk_f32_fp8((int)v, false);
    f32x2 hi = __builtin_amdgcn_cvt_pk_f32_fp8((int)v, true);
    float f0 = lo[0], f1 = lo[1], f2 = hi[0], f3 = hi[1];
    float t0 = f0 + fd0, t1 = f1 + fd1, t2 = f2 + fd2, t3 = f3 + fd3;
    t0 = fmaxf(t0, 0.2f * t0); t1 = fmaxf(t1, 0.2f * t1);
    t2 = fmaxf(t2, 0.2f * t2); t3 = fmaxf(t3, 0.2f * t3);
    float c = t0 * av.x + t1 * av.y + t2 * av.z + t3 * av.w;
    c = reduce16(c);
    float e = __expf(c) * m;
    d_own += e;
    acc0 += e * f0; acc1 += e * f1; acc2 += e * f2; acc3 += e * f3;
  };

  const int beg = rowptr[node], end = rowptr[node + 1];
  int j = beg;
  for (; j + 8 <= end; j += 8) {
    int sa = colsrc[j + half],     sb = colsrc[j + 2 + half];
    int sc = colsrc[j + 4 + half], sd = colsrc[j + 6 + half];
    u32 va = *(const u32*)(fsfd + (size_t)sa * 256 + off);
    u32 vb = *(const u32*)(fsfd + (size_t)sb * 256 + off);
    u32 vc = *(const u32*)(fsfd + (size_t)sc * 256 + off);
    u32 vd = *(const u32*)(fsfd + (size_t)sd * 256 + off);
    edge(va, 1.f); edge(vb, 1.f); edge(vc, 1.f); edge(vd, 1.f);
  }
  for (; j < end; j += 2) {
    int idx = j + half;
    bool valid = idx < end;
    int s = colsrc[valid ? idx : end - 1];
    u32 v = *(const u32*)(fsfd + (size_t)s * 256 + off);
    if (!valid) v = 0;
    edge(v, valid ? 1.f : 0.f);
  }

  acc0 += __shfl_xor(acc0, 32); acc1 += __shfl_xor(acc1, 32);
  acc2 += __shfl_xor(acc2, 32); acc3 += __shfl_xor(acc3, 32);
  d_own += __shfl_xor(d_own, 32);

  float4 bv = *(const float4*)(bias + off);
  float inv = d_own > 0.f ? 1.f / d_own : 0.f;
  float g0 = gelu_f(bv.x + acc0 * inv);
  float g1 = gelu_f(bv.y + acc1 * inv);
  float g2 = gelu_f(bv.z + acc2 * inv);
  float g3 = gelu_f(bv.w + acc3 * inv);
  float v0 = 0.5f * (g0 + __shfl_xor(g0, 16));
  float v1 = 0.5f * (g1 + __shfl_xor(g1, 16));
  float v2 = 0.5f * (g2 + __shfl_xor(g2, 16));
  float v3 = 0.5f * (g3 + __shfl_xor(g3, 16));
  if constexpr (LAYER1) {
    if (l < 16) {
      float4 dv = *(const float4*)(drop + (long)node * 64 + 4 * l);
      short4v s;
      s[0] = (short)f2b(v0 * dv.x); s[1] = (short)f2b(v1 * dv.y);
      s[2] = (short)f2b(v2 * dv.z); s[3] = (short)f2b(v3 * dv.w);
      *(short4v*)((u16*)outv + (long)node * 64 + 4 * l) = s;
    }
  } else {
    float ss = v0 * v0 + v1 * v1 + v2 * v2 + v3 * v3;
    ss = reduce16(ss);
    float sc = 1.f / fmaxf(sqrtf(ss), 1e-12f);
    if (l < 16) {
      float4 o; o.x = v0 * sc; o.y = v1 * sc; o.z = v2 * sc; o.w = v3 * sc;
      *(float4*)((float*)outv + (long)node * 64 + 4 * l) = o;
    }
  }
}

// ================= merged gather stage: gat || sage ==============================
template <bool LAYER1, bool DROP>
__global__ __launch_bounds__(256) void gather_stage(
    const u8* __restrict__ fsfd, const u16* __restrict__ q, const u8* __restrict__ p,
    const int* __restrict__ rowptr, const int* __restrict__ colsrc,
    const float* __restrict__ attn, const float* __restrict__ gbias,
    const float* __restrict__ sbias, const float* __restrict__ gdrop,
    const float* __restrict__ sdrop, void* __restrict__ gout,
    u16* __restrict__ sout) {
  int b = blockIdx.x;
  if (b < NGB_) {
    int node = b * 4 + (threadIdx.x >> 6);
    gat_body<LAYER1>(node, fsfd, rowptr, colsrc, attn, gbias, gdrop, gout);
  } else {
    int node = (b - NGB_) * 4 + (threadIdx.x >> 6);
    sage_body<DROP>(node, q, p, rowptr, colsrc, sbias, sdrop, sout);
  }
}

extern "C" void kernel_launch(void* const* d_in, const int* in_sizes, int n_in,
                              void* d_out, int out_size, void* d_ws, size_t ws_size,
                              hipStream_t stream) {
  const float* feat = (const float*)d_in[0];
  const int*   esrc = (const int*)d_in[1];
  const int*   edst = (const int*)d_in[2];
  const float* Wmt = (const float*)d_in[3],  *bmt = (const float*)d_in[4];
  const float* Wms = (const float*)d_in[5],  *bms = (const float*)d_in[6];
  const float* W1s = (const float*)d_in[7],  *W1n = (const float*)d_in[8],  *b1 = (const float*)d_in[9];
  const float* W2s = (const float*)d_in[10], *W2n = (const float*)d_in[11], *b2 = (const float*)d_in[12];
  const float* g1Ws = (const float*)d_in[13], *g1Wd = (const float*)d_in[14];
  const float* g1a  = (const float*)d_in[15], *g1b  = (const float*)d_in[16];
  const float* g2Ws = (const float*)d_in[17], *g2Wd = (const float*)d_in[18];
  const float* g2a  = (const float*)d_in[19], *g2b  = (const float*)d_in[20];
  const float* W3  = (const float*)d_in[21], *b3 = (const float*)d_in[22];
  const float* dropt = (const float*)d_in[23], *drops = (const float*)d_in[24];

  float* out_t = (float*)d_out;
  float* out_s = out_t + (long)N_ * 64;

  // workspace (u16 units)
  u16* wsh = (u16*)d_ws;
  u16* featbf = wsh;                 // N*128
  u16* hbuf_t = wsh +  6400000;      // N*128
  u16* hbuf_s = wsh + 12800000;      // N*128
  u16* q1     = wsh + 19200000;      // N*64 bf16
  u8*  p1     = (u8*)(wsh + 22400000); // N*64 fp8
  u16* h1     = wsh + 24000000;      // N*64
  u16* q2     = wsh + 27200000;      // N*64
  u8*  p2     = (u8*)(wsh + 30400000); // N*64 fp8
  u16* h2     = wsh + 32000000;      // N*64
  u16* hs1    = wsh + 35200000;      // N*64
  u8*  fsfd8  = (u8*)(wsh + 38400000); // N*256 fp8 (= N*128 u16)
  u16* Wpk    = wsh + 44800000;      // 118784
  int* degi   = (int*)(wsh + 44918784);  // N
  int* cursor = degi + N_;               // N
  int* rowptr = cursor + N_;             // N+1
  int* colsrc = rowptr + N_ + 1;         // E
  int* bsum   = colsrc + E_;             // NB_
  int* bpre   = bsum + NB_;              // NB_+1

  const u16* WpMT = Wpk;             // [Wmt|Wms]
  const u16* WpS1 = Wpk + 32768;     // [W1s|W1n] C-concat
  const u16* WpS2 = Wpk + 49152;     // [W2s|W2n] C-concat
  const u16* WpG1 = Wpk + 57344;
  const u16* WpG2 = Wpk + 90112;
  const u16* WpW3 = Wpk + 106496;

  // ---- prep: degree + packs ----
  (void)hipMemsetAsync(degi, 0, (size_t)(2 * N_) * sizeof(int), stream);
  prep_kernel<<<DEGB_ + PFB_ + 464, 256, 0, stream>>>(edst, degi, feat, featbf,
      Wmt, Wms, W1s, W1n, W2s, W2n, g1Ws, g1Wd, g2Ws, g2Wd, W3, Wpk);
  scan_local<<<NB_, 256, 0, stream>>>(degi, rowptr, bsum);
  scan_block<<<1, 256, 0, stream>>>(bsum, bpre);
  scan_add<<<(N_ + 256) / 256, 256, 0, stream>>>(rowptr, bpre);

  // ---- stage0: mask GEMM || csr_fill ----
  stage0<<<GB_ + CSRB_, 512, 0, stream>>>(featbf, WpMT, bmt, bms, hbuf_t, hbuf_s,
                                          esrc, edst, rowptr, cursor, colsrc);

  // ---- stage1: S1 GEMM (q/p) || G1 GEMM (fp8) ----
  gemm_pair<128, 128><<<2 * GB_, 512, 0, stream>>>(hbuf_t, WpS1, q1, p1,
                                                   hbuf_s, WpG1, fsfd8);
  // ---- stage2: gat1 || sage1 ----
  gather_stage<true, true><<<2 * NGB_, 256, 0, stream>>>(fsfd8, q1, p1, rowptr, colsrc,
      g1a, g1b, b1, drops, dropt, hs1, h1);
  // ---- stage3: S2 GEMM || G2 GEMM ----
  gemm_pair<64, 64><<<2 * GB_, 512, 0, stream>>>(h1, WpS2, q2, p2,
                                                 hs1, WpG2, fsfd8);
  // ---- stage4: gat2 || sage2 ----
  gather_stage<false, false><<<2 * NGB_, 256, 0, stream>>>(fsfd8, q2, p2, rowptr, colsrc,
      g2a, g2b, b2, nullptr, nullptr, out_s, h2);
  // ---- final topology GEMM ----
  final_t<<<GB_, 512, 0, stream>>>(h2, featbf, WpW3, b3, out_t);
}